// Round 20
// baseline (227.501 us; speedup 1.0000x reference)
//
#include <hip/hip_runtime.h>

#define DH 128   // D_IN == D_H == 128
#define TR 32    // rows per tile (per block)

typedef __attribute__((ext_vector_type(8))) short bf16x8;
typedef __attribute__((ext_vector_type(8))) unsigned short u16x8;
typedef __attribute__((ext_vector_type(4))) float f32x4;
typedef __attribute__((ext_vector_type(4))) int   i32x4;

__device__ inline unsigned rnd_bf16(float f){
  unsigned u = __builtin_bit_cast(unsigned, f);
  u += 0x7fffu + ((u >> 16) & 1u);   // RNE
  return u;
}
__device__ inline int pk2(float a, float b){
  unsigned ua = rnd_bf16(a), ub = rnd_bf16(b);
  return (int)((ua >> 16) | (ub & 0xffff0000u));
}
__device__ inline float fsigmoid(float v){
  float e = __builtin_amdgcn_exp2f(v * -1.442695040888963f);
  return __builtin_amdgcn_rcpf(1.0f + e);
}
__device__ inline float ftanhf(float v){
  float e = __builtin_amdgcn_exp2f(v * 2.885390081777927f); // e^{2v}
  return 1.0f - 2.0f * __builtin_amdgcn_rcpf(1.0f + e);
}

// Wf[hs 4][g 4][t 2][ks 8][lane 64] 16B fragments: lane (l15,lg) holds
// ncol = g*128 + hs*32 + t*16 + l15, k = ks*32 + lg*8 .. +8 (k<128: W_x, else W_h).
__global__ void prep_weights(const float* __restrict__ Wxi, const float* __restrict__ Whi, const float* __restrict__ bi,
                             const float* __restrict__ Wxf, const float* __restrict__ Whf, const float* __restrict__ bf_,
                             const float* __restrict__ Wxc, const float* __restrict__ Whc, const float* __restrict__ bc,
                             const float* __restrict__ Wxo, const float* __restrict__ Who, const float* __restrict__ bo,
                             u16x8* __restrict__ Wf, float* __restrict__ bcat){
  int gid  = blockIdx.x * 256 + threadIdx.x;   // 0..16383
  int lane = gid & 63;
  int ks   = (gid >> 6) & 7;
  int t    = (gid >> 9) & 1;
  int g    = (gid >> 10) & 3;
  int hsv  = (gid >> 12) & 3;
  int l15 = lane & 15, lg = lane >> 4;
  int hcol = hsv * 32 + t * 16 + l15;
  int kb   = ks * 32 + lg * 8;
  const float* Wx = (g == 0) ? Wxi : (g == 1) ? Wxf : (g == 2) ? Wxc : Wxo;
  const float* Wh = (g == 0) ? Whi : (g == 1) ? Whf : (g == 2) ? Whc : Who;
  u16x8 o;
  #pragma unroll
  for (int j = 0; j < 8; ++j){
    int k = kb + j;
    float v = (k < 128) ? Wx[k * DH + hcol] : Wh[(k - 128) * DH + hcol];
    o[j] = (unsigned short)(rnd_bf16(v) >> 16);
  }
  Wf[gid] = o;
  if (gid < 512){
    int gg = gid >> 7, hc = gid & 127;
    const float* bp = (gg == 0) ? bi : (gg == 1) ? bf_ : (gg == 2) ? bc : bo;
    bcat[gid] = bp[hc];
  }
}

// One 32-row tile per block. 512 thr = 8 waves; wave w owns h-cols
// [w*16,+16) for all 4 gates (lane-local elementwise; acc = 32 regs/thread).
// __launch_bounds__(512,6): 3 blocks/CU = 24 waves/CU (R15 optimum).
// All global traffic NT; cin staged through cls plane (R19).
// R20 knob: preload ks=0,1 weight fragments before the staging barrier so
// the k-loop's initial L2 latency rides under the input-load window.
__global__ __launch_bounds__(512, 6)
void lstm_fused(const float* __restrict__ x, const float* __restrict__ hin,
                const float* __restrict__ cin, const bf16x8* __restrict__ Wf,
                const float* __restrict__ bcat, float* __restrict__ out, int Btot){
  __shared__ __attribute__((aligned(16))) unsigned char smem[32768];
  bf16x8* xh  = (bf16x8*)smem;              // staging tile, 32 rows x 32 slots (16 KB)
  float*  hls = (float*)smem;               // epilogue h plane (reuse, 16 KB)
  float*  cls = (float*)(smem + 16384);     // c plane: c_in staged, c_new out (16 KB)

  const int tid = threadIdx.x;
  const int l   = tid & 63;
  const int wid = tid >> 6;        // wave id 0..7 = 16-col slice
  const int l15 = l & 15;
  const int lg  = l >> 4;          // 0..3
  const int col = wid * 16 + l15;  // h-col this lane owns
  const size_t rowb = (size_t)blockIdx.x * TR;

  // ---- staging loads (nontemporal): thread covers (row tid>>4, 8 floats)
  const int srow = tid >> 4;       // 0..31
  const int sc   = tid & 15;       // 8-float slot within row
  const float* px = x   + (rowb + srow) * DH + sc * 8;
  const float* ph = hin + (rowb + srow) * DH + sc * 8;
  const float* pc = cin + (rowb + srow) * DH + sc * 8;
  f32x4 x0 = __builtin_nontemporal_load((const f32x4*)(px));
  f32x4 x1 = __builtin_nontemporal_load((const f32x4*)(px + 4));
  f32x4 h0 = __builtin_nontemporal_load((const f32x4*)(ph));
  f32x4 h1 = __builtin_nontemporal_load((const f32x4*)(ph + 4));
  f32x4 c0 = __builtin_nontemporal_load((const f32x4*)(pc));
  f32x4 c1 = __builtin_nontemporal_load((const f32x4*)(pc + 4));

  // ---- weight stream base; preload ks=0,1 (L2 latency hidden pre-barrier)
  const bf16x8* wv = Wf + (size_t)(wid >> 1) * 4096 + l;
  const int tw = wid & 1;
  bf16x8 bwA[4], bwB[4];
  #pragma unroll
  for (int g = 0; g < 4; ++g){
    bwA[g] = wv[(((g * 2 + tw) * 8) + 0) * 64];
    bwB[g] = wv[(((g * 2 + tw) * 8) + 1) * 64];
  }

  // ---- pack x/h + LDS write (slot swizzle s^(row&7)); cin -> cls swizzled
  {
    const int sw = srow & 7;
    i32x4 p;
    p[0] = pk2(x0[0], x0[1]); p[1] = pk2(x0[2], x0[3]);
    p[2] = pk2(x1[0], x1[1]); p[3] = pk2(x1[2], x1[3]);
    xh[srow * 32 + ( sc       ^ sw)] = __builtin_bit_cast(bf16x8, p);
    p[0] = pk2(h0[0], h0[1]); p[1] = pk2(h0[2], h0[3]);
    p[2] = pk2(h1[0], h1[1]); p[3] = pk2(h1[2], h1[3]);
    xh[srow * 32 + ((16 + sc) ^ sw)] = __builtin_bit_cast(bf16x8, p);
    const int swf = sw << 2;            // float-col swizzle
    const int cf  = sc * 8;
    *(f32x4*)&cls[srow * DH + ( cf      ^ swf)] = c0;
    *(f32x4*)&cls[srow * DH + ((cf + 4) ^ swf)] = c1;
  }
  __syncthreads();

  float bb[4];
  #pragma unroll
  for (int g = 0; g < 4; ++g)
    bb[g] = bcat[g * 128 + col];

  f32x4 acc[2][4];
  #pragma unroll
  for (int m = 0; m < 2; ++m)
    #pragma unroll
    for (int g = 0; g < 4; ++g)
      acc[m][g] = (f32x4){0.f, 0.f, 0.f, 0.f};

  #pragma unroll
  for (int ks = 0; ks < 8; ++ks){
    bf16x8 a[2];
    #pragma unroll
    for (int m = 0; m < 2; ++m){
      const int row = m * 16 + l15;
      a[m] = xh[row * 32 + ((ks * 4 + lg) ^ (row & 7))];
    }
    #pragma unroll
    for (int g = 0; g < 4; ++g){
      bf16x8 bw = (ks == 0) ? bwA[g]
                : (ks == 1) ? bwB[g]
                : wv[(((g * 2 + tw) * 8) + ks) * 64];
      acc[0][g] = __builtin_amdgcn_mfma_f32_16x16x32_bf16(a[0], bw, acc[0][g], 0, 0, 0);
      acc[1][g] = __builtin_amdgcn_mfma_f32_16x16x32_bf16(a[1], bw, acc[1][g], 0, 0, 0);
    }
  }
  __syncthreads();   // k-loop LDS reads done; xh reusable as hls; cls staged

  // ---- gate math; c_old from cls, h -> hls, c_new -> cls (same slot)
  #pragma unroll
  for (int m = 0; m < 2; ++m){
    #pragma unroll
    for (int r = 0; r < 4; ++r){
      const int rl = m * 16 + lg * 4 + r;       // local row 0..31
      const int swp = (rl & 7) << 2;
      const int ci = rl * DH + (col ^ swp);
      float cv = cls[ci];
      float gi = acc[m][0][r] + bb[0];
      float gf = acc[m][1][r] + bb[1];
      float gc = acc[m][2][r] + bb[2];
      float go = acc[m][3][r] + bb[3];
      float i_t = fsigmoid(gi);
      float f_t = fsigmoid(gf);
      float g_t = ftanhf(gc);
      float o_t = fsigmoid(go);
      float cn = f_t * cv + i_t * g_t;
      float hn = o_t * ftanhf(cn);
      hls[ci] = hn;
      cls[ci] = cn;
    }
  }
  __syncthreads();

  // ---- stores: wave wid owns rows [wid*4, wid*4+4); each instruction:
  // lane l -> row j*2+(l>>5), colf (l&31)*4 => 1KiB contiguous NT burst.
  const size_t o1 = (size_t)Btot * DH;
  const int wcol = (l & 31) * 4;
  #pragma unroll
  for (int j = 0; j < 2; ++j){
    const int row = wid * 4 + j * 2 + (l >> 5);
    const int sw2 = (row & 7) << 2;
    f32x4 vh = *(const f32x4*)&hls[row * DH + (wcol ^ sw2)];
    f32x4 vc = *(const f32x4*)&cls[row * DH + (wcol ^ sw2)];
    float* po = out + (rowb + row) * DH + wcol;
    __builtin_nontemporal_store(vh, (f32x4*)(po));
    __builtin_nontemporal_store(vh, (f32x4*)(po + o1));
    __builtin_nontemporal_store(vc, (f32x4*)(po + 2 * o1));
  }
}

extern "C" void kernel_launch(void* const* d_in, const int* in_sizes, int n_in,
                              void* d_out, int out_size, void* d_ws, size_t ws_size,
                              hipStream_t stream){
  const float* x  = (const float*)d_in[0];
  const float* ht = (const float*)d_in[1];
  const float* ct = (const float*)d_in[2];
  u16x8* Wf   = (u16x8*)d_ws;                        // 16384 * 16B = 256KB
  float* bcat = (float*)((char*)d_ws + 16384 * 16);  // +2KB
  const int Btot = in_sizes[0] / DH;

  prep_weights<<<64, 256, 0, stream>>>(
      (const float*)d_in[3],  (const float*)d_in[4],  (const float*)d_in[5],
      (const float*)d_in[6],  (const float*)d_in[7],  (const float*)d_in[8],
      (const float*)d_in[9],  (const float*)d_in[10], (const float*)d_in[11],
      (const float*)d_in[12], (const float*)d_in[13], (const float*)d_in[14],
      Wf, bcat);

  lstm_fused<<<Btot / TR, 512, 0, stream>>>(x, ht, ct, (const bf16x8*)Wf, bcat,
                                            (float*)d_out, Btot);
}

// Round 21
// 214.395 us; speedup vs baseline: 1.0611x; 1.0611x over previous
//
#include <hip/hip_runtime.h>

#define DH 128   // D_IN == D_H == 128
#define TR 32    // rows per tile (per block)

typedef __attribute__((ext_vector_type(8))) short bf16x8;
typedef __attribute__((ext_vector_type(8))) unsigned short u16x8;
typedef __attribute__((ext_vector_type(4))) float f32x4;
typedef __attribute__((ext_vector_type(4))) int   i32x4;

__device__ inline unsigned rnd_bf16(float f){
  unsigned u = __builtin_bit_cast(unsigned, f);
  u += 0x7fffu + ((u >> 16) & 1u);   // RNE
  return u;
}
__device__ inline int pk2(float a, float b){
  unsigned ua = rnd_bf16(a), ub = rnd_bf16(b);
  return (int)((ua >> 16) | (ub & 0xffff0000u));
}
__device__ inline float fsigmoid(float v){
  float e = __builtin_amdgcn_exp2f(v * -1.442695040888963f);
  return __builtin_amdgcn_rcpf(1.0f + e);
}
__device__ inline float ftanhf(float v){
  float e = __builtin_amdgcn_exp2f(v * 2.885390081777927f); // e^{2v}
  return 1.0f - 2.0f * __builtin_amdgcn_rcpf(1.0f + e);
}

// Wf[hs 4][g 4][t 2][ks 8][lane 64] 16B fragments: lane (l15,lg) holds
// ncol = g*128 + hs*32 + t*16 + l15, k = ks*32 + lg*8 .. +8 (k<128: W_x, else W_h).
__global__ void prep_weights(const float* __restrict__ Wxi, const float* __restrict__ Whi, const float* __restrict__ bi,
                             const float* __restrict__ Wxf, const float* __restrict__ Whf, const float* __restrict__ bf_,
                             const float* __restrict__ Wxc, const float* __restrict__ Whc, const float* __restrict__ bc,
                             const float* __restrict__ Wxo, const float* __restrict__ Who, const float* __restrict__ bo,
                             u16x8* __restrict__ Wf, float* __restrict__ bcat){
  int gid  = blockIdx.x * 256 + threadIdx.x;   // 0..16383
  int lane = gid & 63;
  int ks   = (gid >> 6) & 7;
  int t    = (gid >> 9) & 1;
  int g    = (gid >> 10) & 3;
  int hsv  = (gid >> 12) & 3;
  int l15 = lane & 15, lg = lane >> 4;
  int hcol = hsv * 32 + t * 16 + l15;
  int kb   = ks * 32 + lg * 8;
  const float* Wx = (g == 0) ? Wxi : (g == 1) ? Wxf : (g == 2) ? Wxc : Wxo;
  const float* Wh = (g == 0) ? Whi : (g == 1) ? Whf : (g == 2) ? Whc : Who;
  u16x8 o;
  #pragma unroll
  for (int j = 0; j < 8; ++j){
    int k = kb + j;
    float v = (k < 128) ? Wx[k * DH + hcol] : Wh[(k - 128) * DH + hcol];
    o[j] = (unsigned short)(rnd_bf16(v) >> 16);
  }
  Wf[gid] = o;
  if (gid < 512){
    int gg = gid >> 7, hc = gid & 127;
    const float* bp = (gg == 0) ? bi : (gg == 1) ? bf_ : (gg == 2) ? bc : bo;
    bcat[gid] = bp[hc];
  }
}

// One 32-row tile per block. 512 thr = 8 waves; wave w owns h-cols
// [w*16,+16) for all 4 gates (lane-local elementwise; acc = 32 regs/thread).
// __launch_bounds__(512,6): 3 blocks/CU = 24 waves/CU (R15 optimum).
// All global traffic NT. cin staged through the cls LDS plane via full-line
// vector NT loads; gate math reads c_old from cls, overwrites slot with c_new.
// (R20's weight preload reverted: barrier's vmcnt(0) drain defeats it.)
__global__ __launch_bounds__(512, 6)
void lstm_fused(const float* __restrict__ x, const float* __restrict__ hin,
                const float* __restrict__ cin, const bf16x8* __restrict__ Wf,
                const float* __restrict__ bcat, float* __restrict__ out, int Btot){
  __shared__ __attribute__((aligned(16))) unsigned char smem[32768];
  bf16x8* xh  = (bf16x8*)smem;              // staging tile, 32 rows x 32 slots (16 KB)
  float*  hls = (float*)smem;               // epilogue h plane (reuse, 16 KB)
  float*  cls = (float*)(smem + 16384);     // c plane: c_in staged, c_new out (16 KB)

  const int tid = threadIdx.x;
  const int l   = tid & 63;
  const int wid = tid >> 6;        // wave id 0..7 = 16-col slice
  const int l15 = l & 15;
  const int lg  = l >> 4;          // 0..3
  const int col = wid * 16 + l15;  // h-col this lane owns
  const size_t rowb = (size_t)blockIdx.x * TR;

  // ---- staging loads (nontemporal): thread covers (row tid>>4, 8 floats)
  const int srow = tid >> 4;       // 0..31
  const int sc   = tid & 15;       // 8-float slot within row
  const float* px = x   + (rowb + srow) * DH + sc * 8;
  const float* ph = hin + (rowb + srow) * DH + sc * 8;
  const float* pc = cin + (rowb + srow) * DH + sc * 8;
  f32x4 x0 = __builtin_nontemporal_load((const f32x4*)(px));
  f32x4 x1 = __builtin_nontemporal_load((const f32x4*)(px + 4));
  f32x4 h0 = __builtin_nontemporal_load((const f32x4*)(ph));
  f32x4 h1 = __builtin_nontemporal_load((const f32x4*)(ph + 4));
  f32x4 c0 = __builtin_nontemporal_load((const f32x4*)(pc));
  f32x4 c1 = __builtin_nontemporal_load((const f32x4*)(pc + 4));

  // ---- pack x/h + LDS write (slot swizzle s^(row&7)); cin -> cls swizzled
  {
    const int sw = srow & 7;
    i32x4 p;
    p[0] = pk2(x0[0], x0[1]); p[1] = pk2(x0[2], x0[3]);
    p[2] = pk2(x1[0], x1[1]); p[3] = pk2(x1[2], x1[3]);
    xh[srow * 32 + ( sc       ^ sw)] = __builtin_bit_cast(bf16x8, p);
    p[0] = pk2(h0[0], h0[1]); p[1] = pk2(h0[2], h0[3]);
    p[2] = pk2(h1[0], h1[1]); p[3] = pk2(h1[2], h1[3]);
    xh[srow * 32 + ((16 + sc) ^ sw)] = __builtin_bit_cast(bf16x8, p);
    const int swf = sw << 2;            // float-col swizzle
    const int cf  = sc * 8;
    *(f32x4*)&cls[srow * DH + ( cf      ^ swf)] = c0;
    *(f32x4*)&cls[srow * DH + ((cf + 4) ^ swf)] = c1;
  }
  __syncthreads();

  float bb[4];
  #pragma unroll
  for (int g = 0; g < 4; ++g)
    bb[g] = bcat[g * 128 + col];

  // wave's weight stream: slice (hs = wid>>1, t = wid&1) of Wf
  const bf16x8* wv = Wf + (size_t)(wid >> 1) * 4096 + l;
  const int tw = wid & 1;

  f32x4 acc[2][4];
  #pragma unroll
  for (int m = 0; m < 2; ++m)
    #pragma unroll
    for (int g = 0; g < 4; ++g)
      acc[m][g] = (f32x4){0.f, 0.f, 0.f, 0.f};

  #pragma unroll
  for (int ks = 0; ks < 8; ++ks){
    bf16x8 a[2];
    #pragma unroll
    for (int m = 0; m < 2; ++m){
      const int row = m * 16 + l15;
      a[m] = xh[row * 32 + ((ks * 4 + lg) ^ (row & 7))];
    }
    #pragma unroll
    for (int g = 0; g < 4; ++g){
      bf16x8 bw = wv[(((g * 2 + tw) * 8) + ks) * 64];
      acc[0][g] = __builtin_amdgcn_mfma_f32_16x16x32_bf16(a[0], bw, acc[0][g], 0, 0, 0);
      acc[1][g] = __builtin_amdgcn_mfma_f32_16x16x32_bf16(a[1], bw, acc[1][g], 0, 0, 0);
    }
  }
  __syncthreads();   // k-loop LDS reads done; xh reusable as hls; cls staged

  // ---- gate math; c_old from cls, h -> hls, c_new -> cls (same slot)
  #pragma unroll
  for (int m = 0; m < 2; ++m){
    #pragma unroll
    for (int r = 0; r < 4; ++r){
      const int rl = m * 16 + lg * 4 + r;       // local row 0..31
      const int swp = (rl & 7) << 2;
      const int ci = rl * DH + (col ^ swp);
      float cv = cls[ci];
      float gi = acc[m][0][r] + bb[0];
      float gf = acc[m][1][r] + bb[1];
      float gc = acc[m][2][r] + bb[2];
      float go = acc[m][3][r] + bb[3];
      float i_t = fsigmoid(gi);
      float f_t = fsigmoid(gf);
      float g_t = ftanhf(gc);
      float o_t = fsigmoid(go);
      float cn = f_t * cv + i_t * g_t;
      float hn = o_t * ftanhf(cn);
      hls[ci] = hn;
      cls[ci] = cn;
    }
  }
  __syncthreads();

  // ---- stores: wave wid owns rows [wid*4, wid*4+4); each instruction:
  // lane l -> row j*2+(l>>5), colf (l&31)*4 => 1KiB contiguous NT burst.
  const size_t o1 = (size_t)Btot * DH;
  const int wcol = (l & 31) * 4;
  #pragma unroll
  for (int j = 0; j < 2; ++j){
    const int row = wid * 4 + j * 2 + (l >> 5);
    const int sw2 = (row & 7) << 2;
    f32x4 vh = *(const f32x4*)&hls[row * DH + (wcol ^ sw2)];
    f32x4 vc = *(const f32x4*)&cls[row * DH + (wcol ^ sw2)];
    float* po = out + (rowb + row) * DH + wcol;
    __builtin_nontemporal_store(vh, (f32x4*)(po));
    __builtin_nontemporal_store(vh, (f32x4*)(po + o1));
    __builtin_nontemporal_store(vc, (f32x4*)(po + 2 * o1));
  }
}

extern "C" void kernel_launch(void* const* d_in, const int* in_sizes, int n_in,
                              void* d_out, int out_size, void* d_ws, size_t ws_size,
                              hipStream_t stream){
  const float* x  = (const float*)d_in[0];
  const float* ht = (const float*)d_in[1];
  const float* ct = (const float*)d_in[2];
  u16x8* Wf   = (u16x8*)d_ws;                        // 16384 * 16B = 256KB
  float* bcat = (float*)((char*)d_ws + 16384 * 16);  // +2KB
  const int Btot = in_sizes[0] / DH;

  prep_weights<<<64, 256, 0, stream>>>(
      (const float*)d_in[3],  (const float*)d_in[4],  (const float*)d_in[5],
      (const float*)d_in[6],  (const float*)d_in[7],  (const float*)d_in[8],
      (const float*)d_in[9],  (const float*)d_in[10], (const float*)d_in[11],
      (const float*)d_in[12], (const float*)d_in[13], (const float*)d_in[14],
      Wf, bcat);

  lstm_fused<<<Btot / TR, 512, 0, stream>>>(x, ht, ct, (const bf16x8*)Wf, bcat,
                                            (float*)d_out, Btot);
}